// Round 18
// baseline (136.244 us; speedup 1.0000x reference)
//
#include <hip/hip_runtime.h>
#include <hip/hip_bf16.h>
#include <stdint.h>

typedef __attribute__((ext_vector_type(8))) short bf16x8;
typedef __attribute__((ext_vector_type(4))) float f32x4;
typedef __attribute__((ext_vector_type(8))) unsigned short ushort8;

__device__ __forceinline__ unsigned short cvt1(float f) {
  union { __hip_bfloat16 b; unsigned short u; } v;
  v.b = __float2bfloat16(f);
  return v.u;
}

__device__ __forceinline__ void gld_lds16(const void* g, void* l) {
  __builtin_amdgcn_global_load_lds(
      (const __attribute__((address_space(1))) unsigned int*)g,
      (__attribute__((address_space(3))) unsigned int*)l,
      16, 0, 0);
}

#define SM_OFS 12.0f  // fixed softmax offset: |q| <= sqrt(127)*|qs| ~= 11.3

// ---------------- cast + transpose W: wt[n][k] = bf16(W[k][n]) ----------------
__global__ void cast_wt_kernel(const float* __restrict__ W,
                               unsigned short* __restrict__ wt) {
  int t = blockIdx.x * blockDim.x + threadIdx.x;  // 512*512 threads
  int n = t >> 9;
  int k = t & 511;
  wt[t] = cvt1(W[k * 512 + n]);
}

// ---------------- fully fused GEMM + bias + relu + LN + softmax-partials ----------------
// Round-18: halve per-step LDS traffic + cvt work. A staged as BF16 via
// register staging (r3 write path, measured 0 conflicts) into r2's exact
// bf16 LDS layout (measured 0 read conflicts): [128 rows][32 k] bf16, 64B
// rows, slot = k8 ^ ((row>>1)&3). Each thread: 16 fp32 of A(t+1) loaded at
// step top (latency covered by compute(t)), 16 cvt (HALF of r17's 32/lane
// read-side), 2 ds_write_b128 after compute, ONE __syncthreads per step.
// LDS/step 48KB vs 72KB; A-frag reads 4 b128/wave vs 8; no cvt in read path.
// B: wt bf16 via gld_lds, 64B rows, slot = k8 ^ ((row>>1)&3) [r14-exact].
// Double buffer 2 x (8KB A + 8KB B) = 32.8KB; (256,3) -> 3 blocks/CU, ~80 VGPR.
// Hazards: WRITE_A/B_gld(t+1) -> buf^1, last read in step t-1, ordered by
// step t-1's barrier; compute(t) reads buf written+barrier'd in step t-1.
// Tile 128x128 (BN=128 == one LN head), BK=32, 16 steps, 4 waves (2x2),
// wave-tile 64x64, acc[4][4]. Epilogue (validated r7/r9/r14/r17) unchanged.
__global__ __launch_bounds__(256, 3) void gemm_fused_kernel(
    const float* __restrict__ x,             // [N][512] fp32
    const unsigned short* __restrict__ wt,   // [512][512] bf16 (W^T)
    const float* __restrict__ bias,          // [512]
    const float* __restrict__ qs,            // [512]
    const int* __restrict__ gidx,            // [N], sorted
    float* __restrict__ NU,                  // [B][512] numerator accum
    float* __restrict__ SA,                  // [B][512] denominator accum
    int N, int mtiles) {
  __shared__ __align__(16) char smem[2 * 16384];  // buf: [A bf16 8KB | B 8KB] x2

  // ---- XCD-grouped bid remap: 4 ntile-peers of an mtile share bid%8 ----
  const int nfull = (mtiles >> 3) << 3;
  const int full_bids = nfull * 4;
  int mtile, ntile;
  {
    const int bid = blockIdx.x;
    if (bid < full_bids) {
      const int chunk = bid >> 5, j = bid & 31;
      mtile = (chunk << 3) + (j & 7);
      ntile = j >> 3;
    } else {
      const int j = bid - full_bids;
      const int rem = mtiles - nfull;
      mtile = nfull + j % rem;
      ntile = j / rem;
    }
  }
  const int m0 = mtile << 7;
  const int n0 = ntile << 7;

  const int tid = threadIdx.x;
  const int lane = tid & 63;
  const int wid = tid >> 6;
  const int wr = wid >> 1;
  const int wc = wid & 1;

  f32x4 acc[4][4];
#pragma unroll
  for (int m = 0; m < 4; m++)
#pragma unroll
    for (int n = 0; n < 4; n++) acc[m][n] = (f32x4){0.f, 0.f, 0.f, 0.f};

  // ---- A reg-stage geometry: thread -> (row = tid>>1, khalf = tid&1) ----
  const int arow = tid >> 1;
  const int akh = tid & 1;
  const float* aSrc = x + (long)min(m0 + arow, N - 1) * 512 + akh * 16;
  const int aswz = (arow >> 1) & 3;
  const int aDst0 = arow * 64 + ((((akh << 1) | 0) ^ aswz) << 4);
  const int aDst1 = arow * 64 + ((((akh << 1) | 1) ^ aswz) << 4);

  // ---- B staging: 2 x 4KB chunks, pre-swizzled global source (r14-exact) ----
  const unsigned short* bP[2];
  int bLds[2];
#pragma unroll
  for (int L = 0; L < 2; L++) {
    const int p = (L << 12) + tid * 16;
    const int row = p >> 6;              // 64B rows, [0,128)
    const int slot = (p >> 4) & 3;
    const int k8 = slot ^ ((row >> 1) & 3);
    bP[L] = wt + (long)(n0 + row) * 512 + k8 * 8;
    bLds[L] = (L << 12) + (wid << 10);
  }

  // ---- fragment read offsets (r2-exact bf16 swizzle, 0 conflicts) ----
  const int rsel = lane & 15;
  const int k8l = lane >> 4;
  int offA[4], offB[4];
#pragma unroll
  for (int m = 0; m < 4; m++) {
    const int ra = wr * 64 + m * 16 + rsel;
    offA[m] = ra * 64 + ((k8l ^ ((ra >> 1) & 3)) << 4);
    const int rb = wc * 64 + m * 16 + rsel;
    offB[m] = rb * 64 + ((k8l ^ ((rb >> 1) & 3)) << 4);
  }

  float4 av[4];

#define LOAD_A(tt)                                          \
  {                                                         \
    const float4* ap = (const float4*)(aSrc + ((tt) << 5)); \
    av[0] = ap[0];                                          \
    av[1] = ap[1];                                          \
    av[2] = ap[2];                                          \
    av[3] = ap[3];                                          \
  }

#define WRITE_A(buf)                                        \
  {                                                         \
    ushort8 o0, o1;                                         \
    o0[0] = cvt1(av[0].x); o0[1] = cvt1(av[0].y);           \
    o0[2] = cvt1(av[0].z); o0[3] = cvt1(av[0].w);           \
    o0[4] = cvt1(av[1].x); o0[5] = cvt1(av[1].y);           \
    o0[6] = cvt1(av[1].z); o0[7] = cvt1(av[1].w);           \
    o1[0] = cvt1(av[2].x); o1[1] = cvt1(av[2].y);           \
    o1[2] = cvt1(av[2].z); o1[3] = cvt1(av[2].w);           \
    o1[4] = cvt1(av[3].x); o1[5] = cvt1(av[3].y);           \
    o1[6] = cvt1(av[3].z); o1[7] = cvt1(av[3].w);           \
    *(ushort8*)(smem + (buf) * 16384 + aDst0) = o0;         \
    *(ushort8*)(smem + (buf) * 16384 + aDst1) = o1;         \
  }

#define STAGE_B(buf, tt)                                                   \
  {                                                                        \
    _Pragma("unroll") for (int L = 0; L < 2; L++)                          \
        gld_lds16(bP[L] + ((tt) << 5),                                     \
                  smem + (buf) * 16384 + 8192 + bLds[L]);                  \
  }

  // ---- prologue: A(0)->regs, B(0)->buf0, write A(0), barrier ----
  LOAD_A(0);
  STAGE_B(0, 0);
  WRITE_A(0);          // compiler inserts vmcnt wait for av
  __syncthreads();     // drains gld_lds + ds_write; buf0 ready

  // ---- K-loop: 16 steps, ONE barrier each; stage covered by compute ----
#pragma unroll
  for (int t = 0; t < 16; t++) {
    if (t < 15) {
      LOAD_A(t + 1);               // global->reg, lands during compute
      STAGE_B((t + 1) & 1, t + 1); // gld_lds, lands during compute
    }

    const char* AsB = smem + (t & 1) * 16384;
    const char* BsB = AsB + 8192;
    bf16x8 af[4], bq[4];
#pragma unroll
    for (int m = 0; m < 4; m++) af[m] = *(const bf16x8*)(AsB + offA[m]);
#pragma unroll
    for (int n = 0; n < 4; n++) bq[n] = *(const bf16x8*)(BsB + offB[n]);
#pragma unroll
    for (int m = 0; m < 4; m++)
#pragma unroll
      for (int n = 0; n < 4; n++)
        acc[m][n] = __builtin_amdgcn_mfma_f32_16x16x32_bf16(
            af[m], bq[n], acc[m][n], 0, 0, 0);

    if (t < 15) {
      WRITE_A((t + 1) & 1);  // buf^1 A; prior readers barrier'd at step t-1
      __syncthreads();       // buf^1 (A ds_write + B gld_lds) ready for t+1
    }
  }
#undef LOAD_A
#undef WRITE_A
#undef STAGE_B

  // ---- epilogue (aliases buf0's A region; barrier first) ----
  __syncthreads();
  int* sgidx = (int*)smem;            // [128]
  float* sS = (float*)(smem + 512);   // [128][2]
  float* sQ = (float*)(smem + 1536);  // [128][2]

  if (tid < 128) {
    const long rg = (long)m0 + tid;
    sgidx[tid] = (rg < N) ? gidx[rg] : 0x7fffffff;
  }

  const int colb = n0 + wc * 64 + rsel;
  float bval[4], qsv[4];
#pragma unroll
  for (int n = 0; n < 4; n++) {
    bval[n] = bias[colb + n * 16];
    qsv[n] = qs[colb + n * 16];
  }

  // per-row partial LN stats over this wave's 64 cols
#pragma unroll
  for (int m = 0; m < 4; m++) {
#pragma unroll
    for (int i = 0; i < 4; i++) {
      const int row_l = wr * 64 + m * 16 + (k8l << 2) + i;
      float s = 0.f, q = 0.f;
#pragma unroll
      for (int n = 0; n < 4; n++) {
        float v = fmaxf(acc[m][n][i] + bval[n], 0.f);
        s += v;
        q += v * v;
      }
#pragma unroll
      for (int d = 1; d < 16; d <<= 1) {
        s += __shfl_xor(s, d, 64);
        q += __shfl_xor(q, d, 64);
      }
      if (rsel == 0) {
        sS[row_l * 2 + wc] = s;
        sQ[row_l * 2 + wc] = q;
      }
    }
  }
  __syncthreads();

  // segmented per-graph reduction + atomics (per-wave wr-half g-range)
  const int lastv = min(127, (int)((long)N - 1 - (long)m0));
  if (wr * 64 <= lastv) {
    const int gmin = sgidx[wr * 64];
    const int gmax = sgidx[min(wr * 64 + 63, lastv)];
    for (int g = gmin; g <= gmax; ++g) {
      float num[4] = {0.f, 0.f, 0.f, 0.f};
      float den[4] = {0.f, 0.f, 0.f, 0.f};
#pragma unroll
      for (int m = 0; m < 4; m++) {
#pragma unroll
        for (int i = 0; i < 4; i++) {
          const int row_l = wr * 64 + m * 16 + (k8l << 2) + i;
          if (sgidx[row_l] == g) {
            const float s = sS[row_l * 2] + sS[row_l * 2 + 1];
            const float qq = sQ[row_l * 2] + sQ[row_l * 2 + 1];
            const float mean = s * (1.f / 128.f);
            const float var = qq * (1.f / 128.f) - mean * mean;
            const float rstd = rsqrtf(var + 1e-5f);
#pragma unroll
            for (int n = 0; n < 4; n++) {
              const float v = fmaxf(acc[m][n][i] + bval[n], 0.f);
              const float qv = (v - mean) * rstd * qsv[n];
              const float e = __expf(qv - SM_OFS);
              num[n] += e * v;
              den[n] += e;
            }
          }
        }
      }
#pragma unroll
      for (int n = 0; n < 4; n++) {
        num[n] += __shfl_xor(num[n], 16, 64);
        num[n] += __shfl_xor(num[n], 32, 64);
        den[n] += __shfl_xor(den[n], 16, 64);
        den[n] += __shfl_xor(den[n], 32, 64);
      }
      if (k8l == 0) {
#pragma unroll
        for (int n = 0; n < 4; n++) {
          atomicAdd(&NU[(long)g * 512 + colb + n * 16], num[n]);
          atomicAdd(&SA[(long)g * 512 + colb + n * 16], den[n]);
        }
      }
    }
  }
}

// ---------------- finalize: out = NU / (SA + eps) ----------------
__global__ void finalize_kernel(const float* __restrict__ NU,
                                const float* __restrict__ SA,
                                float* __restrict__ out, int total) {
  const int i = blockIdx.x * blockDim.x + threadIdx.x;
  if (i < total) out[i] = NU[i] / (SA[i] + 1e-16f);
}

extern "C" void kernel_launch(void* const* d_in, const int* in_sizes, int n_in,
                              void* d_out, int out_size, void* d_ws, size_t ws_size,
                              hipStream_t stream) {
  const float* x = (const float*)d_in[0];
  const float* W = (const float*)d_in[1];
  const float* bias = (const float*)d_in[2];
  const float* qs = (const float*)d_in[3];
  const int* gidx = (const int*)d_in[4];
  const int N = in_sizes[0] / 512;
  const int B = out_size / 512;
  float* out = (float*)d_out;

  char* ws = (char*)d_ws;
  size_t off = 0;
  auto alloc = [&](size_t bytes) {
    char* p = ws + off;
    off += (bytes + 255) & ~(size_t)255;
    return p;
  };
  unsigned short* wt = (unsigned short*)alloc((size_t)512 * 512 * 2);
  float* accbuf = (float*)alloc((size_t)B * 512 * 2 * sizeof(float));
  float* NU = accbuf;
  float* SA = accbuf + (size_t)B * 512;
  (void)ws_size;  // need ~2.6 MB

  hipMemsetAsync(accbuf, 0, (size_t)B * 512 * 2 * sizeof(float), stream);
  cast_wt_kernel<<<(512 * 512) / 256, 256, 0, stream>>>(W, wt);
  const int mtiles = (N + 127) / 128;
  gemm_fused_kernel<<<mtiles * 4, 256, 0, stream>>>(x, wt, bias, qs, gidx, NU,
                                                    SA, N, mtiles);
  const int total = B * 512;
  finalize_kernel<<<(total + 255) / 256, 256, 0, stream>>>(NU, SA, out, total);
}

// Round 19
// 124.409 us; speedup vs baseline: 1.0951x; 1.0951x over previous
//
#include <hip/hip_runtime.h>
#include <hip/hip_bf16.h>
#include <stdint.h>

typedef __attribute__((ext_vector_type(8))) short bf16x8;
typedef __attribute__((ext_vector_type(4))) float f32x4;
typedef __attribute__((ext_vector_type(8))) unsigned short ushort8;

__device__ __forceinline__ unsigned short cvt1(float f) {
  union { __hip_bfloat16 b; unsigned short u; } v;
  v.b = __float2bfloat16(f);
  return v.u;
}

__device__ __forceinline__ void gld_lds16(const void* g, void* l) {
  __builtin_amdgcn_global_load_lds(
      (const __attribute__((address_space(1))) unsigned int*)g,
      (__attribute__((address_space(3))) unsigned int*)l,
      16, 0, 0);
}

#define SM_OFS 12.0f  // fixed softmax offset: |q| <= sqrt(127)*|qs| ~= 11.3

// ---------------- cast + transpose W: wt[n][k] = bf16(W[k][n]) ----------------
__global__ void cast_wt_kernel(const float* __restrict__ W,
                               unsigned short* __restrict__ wt) {
  int t = blockIdx.x * blockDim.x + threadIdx.x;  // 512*512 threads
  int n = t >> 9;
  int k = t & 511;
  wt[t] = cvt1(W[k * 512 + n]);
}

// ---------------- fully fused GEMM + bias + relu + LN + softmax-partials ----------------
// Round-19: BK=64 via TWO stacked r14-exact BK=32 sub-tiles (no new swizzles).
// Rationale (r16/r17/r18 null results): per-step critical path ~= exposed load
// round-trip L (~1200-1500cyc) >> per-step work C; time ~ steps*(L+C)/blocks.
// Doubling BK doubles C per step WITHOUT cutting block concurrency (48KB
// single-buffer -> still 3 blocks/CU) while halving steps: (L+2C)/(3*2C) vs
// (L+C)/(3*C) -> ~1.6x.  8 steps, 2 barriers each, 32 MFMA/step.
// LDS map: As0 16KB @0 | As1 16KB @16384 | Bs0 8KB @32768 | Bs1 8KB @40960;
// each sub-tile layout is r14-exact (A: 128B rows, slot=k4^(row&7);
// B: 64B rows, slot=k8^((row>>1)&3)).
// Tile 128x128 (BN=128 == one LN head), 4 waves (2x2), wave-tile 64x64,
// acc[4][4] (64 AGPR). Epilogue (validated r7/r9/r14/r17/r18) unchanged.
__global__ __launch_bounds__(256, 3) void gemm_fused_kernel(
    const float* __restrict__ x,             // [N][512] fp32
    const unsigned short* __restrict__ wt,   // [512][512] bf16 (W^T)
    const float* __restrict__ bias,          // [512]
    const float* __restrict__ qs,            // [512]
    const int* __restrict__ gidx,            // [N], sorted
    float* __restrict__ NU,                  // [B][512] numerator accum
    float* __restrict__ SA,                  // [B][512] denominator accum
    int N, int mtiles) {
  __shared__ __align__(16) char smem[49152];

  // ---- XCD-grouped bid remap: 4 ntile-peers of an mtile share bid%8 ----
  const int nfull = (mtiles >> 3) << 3;
  const int full_bids = nfull * 4;
  int mtile, ntile;
  {
    const int bid = blockIdx.x;
    if (bid < full_bids) {
      const int chunk = bid >> 5, j = bid & 31;
      mtile = (chunk << 3) + (j & 7);
      ntile = j >> 3;
    } else {
      const int j = bid - full_bids;
      const int rem = mtiles - nfull;
      mtile = nfull + j % rem;
      ntile = j / rem;
    }
  }
  const int m0 = mtile << 7;
  const int n0 = ntile << 7;

  const int tid = threadIdx.x;
  const int lane = tid & 63;
  const int wid = tid >> 6;
  const int wr = wid >> 1;
  const int wc = wid & 1;

  f32x4 acc[4][4];
#pragma unroll
  for (int m = 0; m < 4; m++)
#pragma unroll
    for (int n = 0; n < 4; n++) acc[m][n] = (f32x4){0.f, 0.f, 0.f, 0.f};

  // ---- A staging: 8 x 4KB chunks (chunks 0-3 -> As0 k[0,32), 4-7 -> As1 k[32,64)) ----
  const float* aP[8];
  int aLds[8];
#pragma unroll
  for (int L = 0; L < 8; L++) {
    const int p = ((L & 3) << 12) + tid * 16;  // byte in 16KB sub-tile
    const int row = p >> 7;                    // 128B rows
    const int slot = (p >> 4) & 7;
    const int k4 = slot ^ (row & 7);
    aP[L] = x + (long)min(m0 + row, N - 1) * 512 + k4 * 4 + (L >> 2) * 32;
    aLds[L] = (L >> 2) * 16384 + ((L & 3) << 12) + (wid << 10);
  }

  // ---- B staging: 4 x 4KB chunks (0-1 -> Bs0, 2-3 -> Bs1) ----
  const unsigned short* bP[4];
  int bLds[4];
#pragma unroll
  for (int L = 0; L < 4; L++) {
    const int p = ((L & 1) << 12) + tid * 16;  // byte in 8KB sub-tile
    const int row = p >> 6;                    // 64B rows
    const int slot = (p >> 4) & 3;
    const int k8 = slot ^ ((row >> 1) & 3);
    bP[L] = wt + (long)(n0 + row) * 512 + k8 * 8 + (L >> 1) * 32;
    bLds[L] = 32768 + (L >> 1) * 8192 + ((L & 1) << 12) + (wid << 10);
  }

  // ---- fragment read offsets (r14-exact, per sub-tile) ----
  const int rsel = lane & 15;
  const int k8l = lane >> 4;
  int offA[4], offB[4];
#pragma unroll
  for (int m = 0; m < 4; m++) {
    const int ra = wr * 64 + m * 16 + rsel;
    offA[m] = ra * 128 + (((k8l << 1) ^ (ra & 7)) << 4);  // pair at ^16
    const int rb = wc * 64 + m * 16 + rsel;
    offB[m] = rb * 64 + ((k8l ^ ((rb >> 1) & 3)) << 4);
  }

  // ---- K-loop: 8 steps (BK=64), 2 barriers each, compiler-managed waits ----
#pragma unroll
  for (int t = 0; t < 8; t++) {
#pragma unroll
    for (int L = 0; L < 8; L++) gld_lds16(aP[L] + (t << 6), smem + aLds[L]);
#pragma unroll
    for (int L = 0; L < 4; L++) gld_lds16(bP[L] + (t << 6), smem + bLds[L]);
    __syncthreads();

#pragma unroll
    for (int kk = 0; kk < 2; kk++) {
      const char* AsB = smem + kk * 16384;
      const char* BsB = smem + 32768 + kk * 8192;
      bf16x8 af[4], bq[4];
#pragma unroll
      for (int m = 0; m < 4; m++) {
        const f32x4 r0 = *(const f32x4*)(AsB + offA[m]);
        const f32x4 r1 = *(const f32x4*)(AsB + (offA[m] ^ 16));
        ushort8 u;
        u[0] = cvt1(r0[0]); u[1] = cvt1(r0[1]);
        u[2] = cvt1(r0[2]); u[3] = cvt1(r0[3]);
        u[4] = cvt1(r1[0]); u[5] = cvt1(r1[1]);
        u[6] = cvt1(r1[2]); u[7] = cvt1(r1[3]);
        af[m] = (bf16x8)u;
      }
#pragma unroll
      for (int n = 0; n < 4; n++) bq[n] = *(const bf16x8*)(BsB + offB[n]);
#pragma unroll
      for (int m = 0; m < 4; m++)
#pragma unroll
        for (int n = 0; n < 4; n++)
          acc[m][n] = __builtin_amdgcn_mfma_f32_16x16x32_bf16(
              af[m], bq[n], acc[m][n], 0, 0, 0);
    }
    __syncthreads();
  }

  // ---- epilogue (aliases As0; loop's trailing barrier protects) ----
  int* sgidx = (int*)smem;            // [128]
  float* sS = (float*)(smem + 512);   // [128][2]
  float* sQ = (float*)(smem + 1536);  // [128][2]

  if (tid < 128) {
    const long rg = (long)m0 + tid;
    sgidx[tid] = (rg < N) ? gidx[rg] : 0x7fffffff;
  }

  const int colb = n0 + wc * 64 + rsel;
  float bval[4], qsv[4];
#pragma unroll
  for (int n = 0; n < 4; n++) {
    bval[n] = bias[colb + n * 16];
    qsv[n] = qs[colb + n * 16];
  }

  // per-row partial LN stats over this wave's 64 cols
#pragma unroll
  for (int m = 0; m < 4; m++) {
#pragma unroll
    for (int i = 0; i < 4; i++) {
      const int row_l = wr * 64 + m * 16 + (k8l << 2) + i;
      float s = 0.f, q = 0.f;
#pragma unroll
      for (int n = 0; n < 4; n++) {
        float v = fmaxf(acc[m][n][i] + bval[n], 0.f);
        s += v;
        q += v * v;
      }
#pragma unroll
      for (int d = 1; d < 16; d <<= 1) {
        s += __shfl_xor(s, d, 64);
        q += __shfl_xor(q, d, 64);
      }
      if (rsel == 0) {
        sS[row_l * 2 + wc] = s;
        sQ[row_l * 2 + wc] = q;
      }
    }
  }
  __syncthreads();

  // segmented per-graph reduction + atomics (per-wave wr-half g-range)
  const int lastv = min(127, (int)((long)N - 1 - (long)m0));
  if (wr * 64 <= lastv) {
    const int gmin = sgidx[wr * 64];
    const int gmax = sgidx[min(wr * 64 + 63, lastv)];
    for (int g = gmin; g <= gmax; ++g) {
      float num[4] = {0.f, 0.f, 0.f, 0.f};
      float den[4] = {0.f, 0.f, 0.f, 0.f};
#pragma unroll
      for (int m = 0; m < 4; m++) {
#pragma unroll
        for (int i = 0; i < 4; i++) {
          const int row_l = wr * 64 + m * 16 + (k8l << 2) + i;
          if (sgidx[row_l] == g) {
            const float s = sS[row_l * 2] + sS[row_l * 2 + 1];
            const float qq = sQ[row_l * 2] + sQ[row_l * 2 + 1];
            const float mean = s * (1.f / 128.f);
            const float var = qq * (1.f / 128.f) - mean * mean;
            const float rstd = rsqrtf(var + 1e-5f);
#pragma unroll
            for (int n = 0; n < 4; n++) {
              const float v = fmaxf(acc[m][n][i] + bval[n], 0.f);
              const float qv = (v - mean) * rstd * qsv[n];
              const float e = __expf(qv - SM_OFS);
              num[n] += e * v;
              den[n] += e;
            }
          }
        }
      }
#pragma unroll
      for (int n = 0; n < 4; n++) {
        num[n] += __shfl_xor(num[n], 16, 64);
        num[n] += __shfl_xor(num[n], 32, 64);
        den[n] += __shfl_xor(den[n], 16, 64);
        den[n] += __shfl_xor(den[n], 32, 64);
      }
      if (k8l == 0) {
#pragma unroll
        for (int n = 0; n < 4; n++) {
          atomicAdd(&NU[(long)g * 512 + colb + n * 16], num[n]);
          atomicAdd(&SA[(long)g * 512 + colb + n * 16], den[n]);
        }
      }
    }
  }
}

// ---------------- finalize: out = NU / (SA + eps) ----------------
__global__ void finalize_kernel(const float* __restrict__ NU,
                                const float* __restrict__ SA,
                                float* __restrict__ out, int total) {
  const int i = blockIdx.x * blockDim.x + threadIdx.x;
  if (i < total) out[i] = NU[i] / (SA[i] + 1e-16f);
}

extern "C" void kernel_launch(void* const* d_in, const int* in_sizes, int n_in,
                              void* d_out, int out_size, void* d_ws, size_t ws_size,
                              hipStream_t stream) {
  const float* x = (const float*)d_in[0];
  const float* W = (const float*)d_in[1];
  const float* bias = (const float*)d_in[2];
  const float* qs = (const float*)d_in[3];
  const int* gidx = (const int*)d_in[4];
  const int N = in_sizes[0] / 512;
  const int B = out_size / 512;
  float* out = (float*)d_out;

  char* ws = (char*)d_ws;
  size_t off = 0;
  auto alloc = [&](size_t bytes) {
    char* p = ws + off;
    off += (bytes + 255) & ~(size_t)255;
    return p;
  };
  unsigned short* wt = (unsigned short*)alloc((size_t)512 * 512 * 2);
  float* accbuf = (float*)alloc((size_t)B * 512 * 2 * sizeof(float));
  float* NU = accbuf;
  float* SA = accbuf + (size_t)B * 512;
  (void)ws_size;  // need ~2.6 MB

  hipMemsetAsync(accbuf, 0, (size_t)B * 512 * 2 * sizeof(float), stream);
  cast_wt_kernel<<<(512 * 512) / 256, 256, 0, stream>>>(W, wt);
  const int mtiles = (N + 127) / 128;
  gemm_fused_kernel<<<mtiles * 4, 256, 0, stream>>>(x, wt, bias, qs, gidx, NU,
                                                    SA, N, mtiles);
  const int total = B * 512;
  finalize_kernel<<<(total + 255) / 256, 256, 0, stream>>>(NU, SA, out, total);
}